// Round 1
// baseline (38.472 us; speedup 1.0000x reference)
//
#include <hip/hip_runtime.h>
#include <math.h>

#define N_PTS   8192
#define BLK     256
#define ITILES  (N_PTS / BLK)     // 32
#define NSLICE  32
#define JCHUNK  (N_PTS / NSLICE)  // 256
#define DIST_BLOCKS (2 * ITILES * NSLICE)  // 2048

// ---------------------------------------------------------------- init ----
__global__ void chamfer_init_kernel(unsigned int* __restrict__ dist, int n) {
    int i = blockIdx.x * blockDim.x + threadIdx.x;
    if (i < n) dist[i] = 0x7F800000u;  // +inf bit pattern
}

// ---------------------------------------------------------------- dist ----
// Each block: one (direction, i-tile, j-chunk). Thread t owns point
// i = itile*256 + t of cloud `a` and scans JCHUNK points of cloud `b`,
// whose index is wave-uniform -> compiler emits scalar loads (SMEM).
// Min is tracked in 4 independent accumulators to break the dep chain,
// then folded and atomicMin'd (uint-bits, valid since d2 >= 0).
__global__ __launch_bounds__(BLK) void chamfer_dist_kernel(
        const float* __restrict__ A, const float* __restrict__ B,
        unsigned int* __restrict__ dist1, unsigned int* __restrict__ dist2) {
    int bid = blockIdx.x;
    const int half = ITILES * NSLICE;
    int dir = (bid >= half) ? 1 : 0;
    if (dir) bid -= half;

    const float* __restrict__ a = dir ? B : A;
    const float* __restrict__ b = dir ? A : B;
    unsigned int* __restrict__ dmin = dir ? dist2 : dist1;

    int itile = bid / NSLICE;
    int slice = bid % NSLICE;
    int i = itile * BLK + (int)threadIdx.x;

    float ax = a[3 * i + 0];
    float ay = a[3 * i + 1];
    float az = a[3 * i + 2];

    const float inf = __builtin_inff();
    float m0 = inf, m1 = inf, m2 = inf, m3 = inf;

    int j0 = slice * JCHUNK;
    const float* bp = b + 3 * j0;
    #pragma unroll 4
    for (int j = 0; j < JCHUNK; j += 4) {
        // 4 points, 12 floats, all wave-uniform addresses
        float b0x = bp[0],  b0y = bp[1],  b0z = bp[2];
        float b1x = bp[3],  b1y = bp[4],  b1z = bp[5];
        float b2x = bp[6],  b2y = bp[7],  b2z = bp[8];
        float b3x = bp[9],  b3y = bp[10], b3z = bp[11];
        bp += 12;

        float dx, dy, dz, d2;
        dx = ax - b0x; dy = ay - b0y; dz = az - b0z;
        d2 = dx * dx; d2 = fmaf(dy, dy, d2); d2 = fmaf(dz, dz, d2);
        m0 = fminf(m0, d2);
        dx = ax - b1x; dy = ay - b1y; dz = az - b1z;
        d2 = dx * dx; d2 = fmaf(dy, dy, d2); d2 = fmaf(dz, dz, d2);
        m1 = fminf(m1, d2);
        dx = ax - b2x; dy = ay - b2y; dz = az - b2z;
        d2 = dx * dx; d2 = fmaf(dy, dy, d2); d2 = fmaf(dz, dz, d2);
        m2 = fminf(m2, d2);
        dx = ax - b3x; dy = ay - b3y; dz = az - b3z;
        d2 = dx * dx; d2 = fmaf(dy, dy, d2); d2 = fmaf(dz, dz, d2);
        m3 = fminf(m3, d2);
    }
    float m = fminf(fminf(m0, m1), fminf(m2, m3));
    atomicMin(&dmin[i], __float_as_uint(m));
}

// -------------------------------------------------------------- reduce ----
__global__ __launch_bounds__(BLK) void chamfer_reduce_kernel(
        const unsigned int* __restrict__ dist1,
        const unsigned int* __restrict__ dist2,
        const int* __restrict__ curp, const int* __restrict__ subp,
        float* __restrict__ out) {
    __shared__ float sh1[BLK / 64], sh2[BLK / 64];
    int t = (int)threadIdx.x;
    float s1 = 0.0f, s2 = 0.0f;
    for (int i = t; i < N_PTS; i += BLK) {
        s1 += sqrtf(__uint_as_float(dist1[i]));
        s2 += sqrtf(__uint_as_float(dist2[i]));
    }
    #pragma unroll
    for (int off = 32; off > 0; off >>= 1) {
        s1 += __shfl_down(s1, off, 64);
        s2 += __shfl_down(s2, off, 64);
    }
    int wid = t >> 6, lane = t & 63;
    if (lane == 0) { sh1[wid] = s1; sh2[wid] = s2; }
    __syncthreads();
    if (t == 0) {
        float t1 = 0.0f, t2 = 0.0f;
        #pragma unroll
        for (int w = 0; w < BLK / 64; ++w) { t1 += sh1[w]; t2 += sh2[w]; }
        int e = curp[0] / subp[0];
        double scale = 10.0 / pow(0.99, (double)e);
        double loss = ((double)t1 / N_PTS + (double)t2 / N_PTS) * 0.5;
        out[0] = (float)(loss * scale);
    }
}

// -------------------------------------------------------------- launch ----
extern "C" void kernel_launch(void* const* d_in, const int* in_sizes, int n_in,
                              void* d_out, int out_size, void* d_ws, size_t ws_size,
                              hipStream_t stream) {
    const float* target = (const float*)d_in[0];   // (1, 8192, 3) f32
    const float* output = (const float*)d_in[1];   // (1, 8192, 3) f32
    const int*   curp   = (const int*)d_in[2];
    const int*   subp   = (const int*)d_in[3];
    float* out = (float*)d_out;

    unsigned int* dist1 = (unsigned int*)d_ws;          // 8192 u32
    unsigned int* dist2 = dist1 + N_PTS;                // 8192 u32

    chamfer_init_kernel<<<(2 * N_PTS + BLK - 1) / BLK, BLK, 0, stream>>>(dist1, 2 * N_PTS);
    chamfer_dist_kernel<<<DIST_BLOCKS, BLK, 0, stream>>>(target, output, dist1, dist2);
    chamfer_reduce_kernel<<<1, BLK, 0, stream>>>(dist1, dist2, curp, subp, out);
}

// Round 2
// 31.725 us; speedup vs baseline: 1.2127x; 1.2127x over previous
//
#include <hip/hip_runtime.h>
#include <math.h>

#define N_PTS   8192
#define BLK     256
#define ITILES  (N_PTS / BLK)     // 32 i-tiles per direction
#define NSLICE  32
#define JCHUNK  (N_PTS / NSLICE)  // 256
#define HALF    (ITILES * NSLICE) // 1024 blocks per direction
#define DIST_BLOCKS (2 * HALF)    // 2048
#define RBLK    1024

// ---------------------------------------------------- precompute + init ----
// P[0..8192)  = target points packed as {x, y, z, |p|^2}
// P[8192..16384) = output points packed likewise.
// dmin[0..16384) = +inf bits.
__global__ __launch_bounds__(BLK) void chamfer_prep_kernel(
        const float* __restrict__ target, const float* __restrict__ output,
        float4* __restrict__ P, unsigned int* __restrict__ dmin) {
    int i = blockIdx.x * blockDim.x + threadIdx.x;  // 0 .. 16383
    const float* src = (i < N_PTS) ? target : output;
    int k = (i < N_PTS) ? i : (i - N_PTS);
    float x = src[3 * k + 0];
    float y = src[3 * k + 1];
    float z = src[3 * k + 2];
    float n2 = fmaf(x, x, fmaf(y, y, z * z));
    P[i] = make_float4(x, y, z, n2);
    dmin[i] = 0x7F800000u;  // +inf
}

// ---------------------------------------------------------------- dist ----
// d^2 = |a|^2 + |b|^2 - 2 a.b  (the reference's own formula).
// Per-thread |a|^2 is a constant offset -> pulled out of the min.
// Inner loop per b-point: 3 FMA + 1 min = 4 VALU ops, one uniform float4 load.
__global__ __launch_bounds__(BLK) void chamfer_dist_kernel(
        const float4* __restrict__ P, unsigned int* __restrict__ dmin) {
    int bid = blockIdx.x;
    int dir = (bid >= HALF) ? 1 : 0;
    if (dir) bid -= HALF;
    int aoff = dir ? N_PTS : 0;
    int boff = dir ? 0 : N_PTS;

    int itile = bid / NSLICE;
    int slice = bid % NSLICE;
    int i = itile * BLK + (int)threadIdx.x;

    float4 a = P[aoff + i];
    float axm = -2.0f * a.x;
    float aym = -2.0f * a.y;
    float azm = -2.0f * a.z;

    const float inf = __builtin_inff();
    float m0 = inf, m1 = inf, m2 = inf, m3 = inf;

    const float4* __restrict__ bp = P + boff + slice * JCHUNK;  // wave-uniform
    #pragma unroll 4
    for (int j = 0; j < JCHUNK; j += 4) {
        float4 b0 = bp[j + 0];
        float4 b1 = bp[j + 1];
        float4 b2 = bp[j + 2];
        float4 b3 = bp[j + 3];
        m0 = fminf(m0, fmaf(axm, b0.x, fmaf(aym, b0.y, fmaf(azm, b0.z, b0.w))));
        m1 = fminf(m1, fmaf(axm, b1.x, fmaf(aym, b1.y, fmaf(azm, b1.z, b1.w))));
        m2 = fminf(m2, fmaf(axm, b2.x, fmaf(aym, b2.y, fmaf(azm, b2.z, b2.w))));
        m3 = fminf(m3, fmaf(axm, b3.x, fmaf(aym, b3.y, fmaf(azm, b3.z, b3.w))));
    }
    float m = fminf(fminf(m0, m1), fminf(m2, m3));
    float d2 = fmaxf(a.w + m, 0.0f);  // add |a|^2 back, clamp negatives
    atomicMin(&dmin[aoff + i], __float_as_uint(d2));
}

// -------------------------------------------------------------- reduce ----
__global__ __launch_bounds__(RBLK) void chamfer_reduce_kernel(
        const unsigned int* __restrict__ dmin,
        const int* __restrict__ curp, const int* __restrict__ subp,
        float* __restrict__ out) {
    __shared__ float sh1[RBLK / 64], sh2[RBLK / 64];
    int t = (int)threadIdx.x;
    float s1 = 0.0f, s2 = 0.0f;
    for (int i = t; i < N_PTS; i += RBLK) {
        s1 += sqrtf(__uint_as_float(dmin[i]));
        s2 += sqrtf(__uint_as_float(dmin[N_PTS + i]));
    }
    #pragma unroll
    for (int off = 32; off > 0; off >>= 1) {
        s1 += __shfl_down(s1, off, 64);
        s2 += __shfl_down(s2, off, 64);
    }
    int wid = t >> 6, lane = t & 63;
    if (lane == 0) { sh1[wid] = s1; sh2[wid] = s2; }
    __syncthreads();
    if (t == 0) {
        float t1 = 0.0f, t2 = 0.0f;
        #pragma unroll
        for (int w = 0; w < RBLK / 64; ++w) { t1 += sh1[w]; t2 += sh2[w]; }
        int e = curp[0] / subp[0];
        double scale = 10.0 / pow(0.99, (double)e);
        double loss = ((double)t1 / N_PTS + (double)t2 / N_PTS) * 0.5;
        out[0] = (float)(loss * scale);
    }
}

// -------------------------------------------------------------- launch ----
extern "C" void kernel_launch(void* const* d_in, const int* in_sizes, int n_in,
                              void* d_out, int out_size, void* d_ws, size_t ws_size,
                              hipStream_t stream) {
    const float* target = (const float*)d_in[0];   // (1, 8192, 3) f32
    const float* output = (const float*)d_in[1];   // (1, 8192, 3) f32
    const int*   curp   = (const int*)d_in[2];
    const int*   subp   = (const int*)d_in[3];
    float* out = (float*)d_out;

    // Workspace layout: float4 P[16384] (256 KB), then uint dmin[16384] (64 KB).
    float4* P = (float4*)d_ws;
    unsigned int* dmin = (unsigned int*)(P + 2 * N_PTS);

    chamfer_prep_kernel<<<2 * N_PTS / BLK, BLK, 0, stream>>>(target, output, P, dmin);
    chamfer_dist_kernel<<<DIST_BLOCKS, BLK, 0, stream>>>(P, dmin);
    chamfer_reduce_kernel<<<1, RBLK, 0, stream>>>(dmin, curp, subp, out);
}